// Round 1
// baseline (602.240 us; speedup 1.0000x reference)
//
#include <hip/hip_runtime.h>
#include <hip/hip_bf16.h>
#include <stdint.h>

typedef __bf16 bf16x8 __attribute__((ext_vector_type(8)));
typedef float f32x4 __attribute__((ext_vector_type(4)));

#define NB_H 16
#define NB_KV 4
#define NB_HD 128
#define NB_B 2
#define NB_S 2048
#define NB_D 2048
#define NB_M (NB_B*NB_S)   /* 4096 */
#define NB_NQKV 3072
#define CAPF 50.0f
#define SCALEF 0.08838834764831845f

__device__ __forceinline__ ushort f2bf(float x){
  uint32_t u = __float_as_uint(x);
  u += 0x7fffu + ((u >> 16) & 1u);
  return (ushort)(u >> 16);
}
__device__ __forceinline__ float bf2f(ushort u){
  return __uint_as_float(((uint32_t)u) << 16);
}
__device__ __forceinline__ void gload_lds16(const void* g, void* l){
  __builtin_amdgcn_global_load_lds(
      (const __attribute__((address_space(1))) uint32_t*)g,
      (__attribute__((address_space(3))) uint32_t*)l, 16, 0, 0);
}

// ---------------- fp32 -> bf16 conversion ----------------
__global__ __launch_bounds__(256) void cvt_kernel(const float* __restrict__ in,
                                                  ushort* __restrict__ out, int n){
  int idx = blockIdx.x * blockDim.x + threadIdx.x;
  int i4 = idx * 4;
  if (i4 >= n) return;
  float4 v = *(const float4*)(in + i4);
  ushort4 o;
  o.x = f2bf(v.x); o.y = f2bf(v.y); o.z = f2bf(v.z); o.w = f2bf(v.w);
  *(ushort4*)(out + i4) = o;
}

// ---------------- bf16 GEMM: C[M][N] = A[M][K] * B[N][K]^T ----------------
// 128x128 tile, BK=32, 4 waves (2x2), each wave 64x64 = 4x4 MFMA tiles (m97 structure)
__global__ __launch_bounds__(256) void gemm_bt(const ushort* __restrict__ A,
                                               const ushort* __restrict__ Bw,
                                               ushort* __restrict__ Cb,
                                               float* __restrict__ Cf,
                                               int M, int N, int K){
  __shared__ ushort As[128 * 32];
  __shared__ ushort Bs[128 * 32];
  int tid = threadIdx.x;
  int w = tid >> 6, l = tid & 63;
  int lr = l & 15, lk = l >> 4;
  int row0 = blockIdx.y * 128, col0 = blockIdx.x * 128;
  int wm = w >> 1, wn = w & 1;

  f32x4 acc[4][4];
#pragma unroll
  for (int mi = 0; mi < 4; ++mi)
#pragma unroll
    for (int nj = 0; nj < 4; ++nj)
      acc[mi][nj] = f32x4{0.f, 0.f, 0.f, 0.f};

  for (int k0 = 0; k0 < K; k0 += 32) {
#pragma unroll
    for (int c = 0; c < 2; ++c) {
      int off = w * 2048 + c * 1024 + l * 16;  // byte offset into 8KB tile
      int r = off >> 6;                        // row 0..127
      int cb = off & 63;                       // byte within 64B row
      gload_lds16(A + (size_t)(row0 + r) * K + k0 + (cb >> 1), (char*)As + off);
      gload_lds16(Bw + (size_t)(col0 + r) * K + k0 + (cb >> 1), (char*)Bs + off);
    }
    __syncthreads();
    bf16x8 af[4], bfr[4];
#pragma unroll
    for (int mi = 0; mi < 4; ++mi)
      af[mi] = *(const bf16x8*)(As + (wm * 64 + mi * 16 + lr) * 32 + lk * 8);
#pragma unroll
    for (int nj = 0; nj < 4; ++nj)
      bfr[nj] = *(const bf16x8*)(Bs + (wn * 64 + nj * 16 + lr) * 32 + lk * 8);
#pragma unroll
    for (int mi = 0; mi < 4; ++mi)
#pragma unroll
      for (int nj = 0; nj < 4; ++nj)
        acc[mi][nj] = __builtin_amdgcn_mfma_f32_16x16x32_bf16(af[mi], bfr[nj], acc[mi][nj], 0, 0, 0);
    __syncthreads();
  }

#pragma unroll
  for (int mi = 0; mi < 4; ++mi)
#pragma unroll
    for (int nj = 0; nj < 4; ++nj)
#pragma unroll
      for (int i = 0; i < 4; ++i) {
        int r = row0 + wm * 64 + mi * 16 + lk * 4 + i;
        int c = col0 + wn * 64 + nj * 16 + lr;
        float v = acc[mi][nj][i];
        if (Cb) Cb[(size_t)r * N + c] = f2bf(v);
        else    Cf[(size_t)r * N + c] = v;
      }
}

// ---------------- RoPE in-place on Q (heads 0..15) and K (heads 16..19) ----------------
__global__ __launch_bounds__(256) void rope_kernel(ushort* __restrict__ qkv,
                                                   const float* __restrict__ cosb,
                                                   const float* __restrict__ sinb){
  int idx = blockIdx.x * blockDim.x + threadIdx.x;  // 4096 * 20 * 64
  if (idx >= NB_M * 20 * 64) return;
  int row = idx / 1280;
  int rem = idx - row * 1280;
  int head = rem >> 6;        // 0..19 -> cols head*128 (q then k, contiguous)
  int d = rem & 63;
  size_t base = (size_t)row * NB_NQKV + head * 128 + d;
  float a = bf2f(qkv[base]);
  float b = bf2f(qkv[base + 64]);
  float c = cosb[row * 128 + d];
  float s = sinb[row * 128 + d];
  qkv[base]      = f2bf(a * c - b * s);
  qkv[base + 64] = f2bf(b * c + a * s);
}

// ---------------- V transpose: vt[b][kv][d][s] from qkv cols 2560.. ----------------
__global__ __launch_bounds__(256) void vtrans_kernel(const ushort* __restrict__ qkv,
                                                     ushort* __restrict__ vt){
  __shared__ ushort tile[64 * 136];
  int bid = blockIdx.x;         // b*4*32
  int s0 = (bid & 31) * 64;
  int kvh = (bid >> 5) & 3;
  int b = bid >> 7;
  int tid = threadIdx.x;
#pragma unroll
  for (int i = 0; i < 4; ++i) {
    int g = tid + i * 256;      // 64 rows x 16 chunks of 16B
    int r = g >> 4, c = g & 15;
    *(uint4*)(tile + r * 136 + c * 8) =
        *(const uint4*)(qkv + (size_t)(b * NB_S + s0 + r) * NB_NQKV + 2560 + kvh * 128 + c * 8);
  }
  __syncthreads();
#pragma unroll
  for (int i = 0; i < 4; ++i) {
    int g = tid + i * 256;      // 128 d-rows x 8 chunks
    int dd = g >> 3, c = g & 7;
    union { ushort u[8]; uint4 v; } tmp;
#pragma unroll
    for (int j = 0; j < 8; ++j) tmp.u[j] = tile[(c * 8 + j) * 136 + dd];
    *(uint4*)(vt + ((size_t)(b * NB_KV + kvh) * NB_HD + dd) * NB_S + s0 + c * 8) = tmp.v;
  }
}

// ---------------- flash attention with tanh soft-cap, causal, GQA ----------------
// grid: b*H*(S/64); 4 waves, wave w owns q rows [q0+16w, q0+16w+16), BK=64
__global__ __launch_bounds__(256) void attn_kernel(const ushort* __restrict__ qkv,
                                                   const ushort* __restrict__ vt,
                                                   ushort* __restrict__ obuf){
  __shared__ ushort Ks[64 * 136];   // [kv][hd] padded
  __shared__ ushort Vs[128 * 72];   // [hd][kv] padded
  __shared__ ushort Ps[4 * 16 * 72];// per-wave P tile, padded
  int tid = threadIdx.x;
  int w = tid >> 6, l = tid & 63;
  int lr = l & 15, lk = l >> 4;
  int bidx = blockIdx.x;
  int qt = bidx & 31;
  int h = (bidx >> 5) & 15;
  int b = bidx >> 9;
  int q0 = qt * 64;
  int kvh = h >> 2;

  // Q fragments (16 rows x 128) in registers
  bf16x8 qf[4];
  {
    size_t qbase = (size_t)(b * NB_S + q0 + w * 16 + lr) * NB_NQKV + h * 128;
#pragma unroll
    for (int c = 0; c < 4; ++c)
      qf[c] = *(const bf16x8*)(qkv + qbase + c * 32 + lk * 8);
  }

  float m_run[4], l_run[4];
  f32x4 acc_o[8];
#pragma unroll
  for (int i = 0; i < 4; ++i) { m_run[i] = -1e30f; l_run[i] = 0.f; }
#pragma unroll
  for (int dt = 0; dt < 8; ++dt) acc_o[dt] = f32x4{0.f, 0.f, 0.f, 0.f};

  int ktmax = q0 >> 6;  // inclusive
  for (int kt = 0; kt <= ktmax; ++kt) {
    int s0 = kt * 64;
    // stage K tile [64][128] and V^T tile [128][64]
#pragma unroll
    for (int i4 = 0; i4 < 4; ++i4) {
      int g = tid + i4 * 256;
      int r = g >> 4, c = g & 15;
      *(uint4*)(Ks + r * 136 + c * 8) =
          *(const uint4*)(qkv + (size_t)(b * NB_S + s0 + r) * NB_NQKV + 2048 + kvh * 128 + c * 8);
      int r2 = g >> 3, c2 = g & 7;
      *(uint4*)(Vs + r2 * 72 + c2 * 8) =
          *(const uint4*)(vt + ((size_t)(b * NB_KV + kvh) * NB_HD + r2) * NB_S + s0 + c2 * 8);
    }
    __syncthreads();

    // S = Q K^T  (16x64 per wave)
    f32x4 sa[4];
#pragma unroll
    for (int nt = 0; nt < 4; ++nt) sa[nt] = f32x4{0.f, 0.f, 0.f, 0.f};
#pragma unroll
    for (int nt = 0; nt < 4; ++nt)
#pragma unroll
      for (int kc = 0; kc < 4; ++kc) {
        bf16x8 kf = *(const bf16x8*)(Ks + (nt * 16 + lr) * 136 + kc * 32 + lk * 8);
        sa[nt] = __builtin_amdgcn_mfma_f32_16x16x32_bf16(qf[kc], kf, sa[nt], 0, 0, 0);
      }

    // soft-cap + mask
    float sc[4][4];
#pragma unroll
    for (int nt = 0; nt < 4; ++nt)
#pragma unroll
      for (int i = 0; i < 4; ++i) {
        float x = sa[nt][i] * (SCALEF / CAPF);
        x = fminf(fmaxf(x, -10.f), 10.f);
        float t = __expf(2.f * x);
        float capped = CAPF * ((t - 1.f) / (t + 1.f));
        int qrow = q0 + w * 16 + lk * 4 + i;
        int kcol = s0 + nt * 16 + lr;
        sc[nt][i] = (kcol <= qrow) ? capped : -1e30f;
      }

    // online softmax
    float fac[4];
#pragma unroll
    for (int i = 0; i < 4; ++i) {
      float v = fmaxf(fmaxf(sc[0][i], sc[1][i]), fmaxf(sc[2][i], sc[3][i]));
      v = fmaxf(v, __shfl_xor(v, 1));
      v = fmaxf(v, __shfl_xor(v, 2));
      v = fmaxf(v, __shfl_xor(v, 4));
      v = fmaxf(v, __shfl_xor(v, 8));
      float mn = fmaxf(m_run[i], v);
      fac[i] = __expf(m_run[i] - mn);
      m_run[i] = mn;
    }
#pragma unroll
    for (int i = 0; i < 4; ++i) {
      float rs = 0.f;
#pragma unroll
      for (int nt = 0; nt < 4; ++nt) {
        float p = __expf(sc[nt][i] - m_run[i]);
        Ps[w * 1152 + (lk * 4 + i) * 72 + nt * 16 + lr] = f2bf(p);
        rs += p;
      }
      rs += __shfl_xor(rs, 1);
      rs += __shfl_xor(rs, 2);
      rs += __shfl_xor(rs, 4);
      rs += __shfl_xor(rs, 8);
      l_run[i] = l_run[i] * fac[i] + rs;
    }
#pragma unroll
    for (int dt = 0; dt < 8; ++dt)
#pragma unroll
      for (int i = 0; i < 4; ++i) acc_o[dt][i] *= fac[i];

    // O += P V  (A-frag of P re-read from LDS in MFMA layout)
#pragma unroll
    for (int kc2 = 0; kc2 < 2; ++kc2) {
      bf16x8 pf = *(const bf16x8*)(Ps + w * 1152 + lr * 72 + kc2 * 32 + lk * 8);
#pragma unroll
      for (int dt = 0; dt < 8; ++dt) {
        bf16x8 vf = *(const bf16x8*)(Vs + (dt * 16 + lr) * 72 + kc2 * 32 + lk * 8);
        acc_o[dt] = __builtin_amdgcn_mfma_f32_16x16x32_bf16(pf, vf, acc_o[dt], 0, 0, 0);
      }
    }
    __syncthreads();
  }

#pragma unroll
  for (int dt = 0; dt < 8; ++dt)
#pragma unroll
    for (int i = 0; i < 4; ++i) {
      int qrow = q0 + w * 16 + lk * 4 + i;
      float v = acc_o[dt][i] / l_run[i];
      obuf[(size_t)(b * NB_S + qrow) * NB_D + h * 128 + dt * 16 + lr] = f2bf(v);
    }
}

// ---------------- host launch ----------------
extern "C" void kernel_launch(void* const* d_in, const int* in_sizes, int n_in,
                              void* d_out, int out_size, void* d_ws, size_t ws_size,
                              hipStream_t stream) {
  const float* hs   = (const float*)d_in[0];
  const float* cosb = (const float*)d_in[1];
  const float* sinb = (const float*)d_in[2];
  const float* Wq   = (const float*)d_in[3];
  const float* Wk   = (const float*)d_in[4];
  const float* Wv   = (const float*)d_in[5];
  const float* Wo   = (const float*)d_in[6];
  float* out = (float*)d_out;
  char* ws = (char*)d_ws;

  // workspace layout (bytes)
  ushort* hsb  = (ushort*)(ws + 0);           // 4096x2048 bf16   (16.78 MB)
  ushort* wqkv = (ushort*)(ws + 16777216);    // 3072x2048 bf16   (12.58 MB)
  ushort* wob  = (ushort*)(ws + 29360128);    // 2048x2048 bf16   ( 8.39 MB)
  ushort* qkvb = (ushort*)(ws + 37748736);    // 4096x3072 bf16   (25.17 MB)
  ushort* vtb  = (ushort*)(ws + 62914560);    // 2x4x128x2048 bf16( 4.19 MB)
  ushort* ob   = (ushort*)(ws + 67108864);    // 4096x2048 bf16   (16.78 MB)

  // 1) convert inputs to bf16 (Wq/Wk/Wv concatenated into one [3072][2048])
  cvt_kernel<<<(NB_M * NB_D / 4 + 255) / 256, 256, 0, stream>>>(hs, hsb, NB_M * NB_D);
  cvt_kernel<<<(NB_H * NB_HD * NB_D / 4 + 255) / 256, 256, 0, stream>>>(Wq, wqkv, NB_H * NB_HD * NB_D);
  cvt_kernel<<<(NB_KV * NB_HD * NB_D / 4 + 255) / 256, 256, 0, stream>>>(Wk, wqkv + 2048 * 2048, NB_KV * NB_HD * NB_D);
  cvt_kernel<<<(NB_KV * NB_HD * NB_D / 4 + 255) / 256, 256, 0, stream>>>(Wv, wqkv + 2560 * 2048, NB_KV * NB_HD * NB_D);
  cvt_kernel<<<(NB_D * NB_D / 4 + 255) / 256, 256, 0, stream>>>(Wo, wob, NB_D * NB_D);

  // 2) QKV projection: [4096][2048] x [3072][2048]^T -> [4096][3072] bf16
  gemm_bt<<<dim3(NB_NQKV / 128, NB_M / 128), 256, 0, stream>>>(hsb, wqkv, qkvb, nullptr,
                                                               NB_M, NB_NQKV, NB_D);
  // 3) RoPE on Q and K columns in place
  rope_kernel<<<(NB_M * 20 * 64 + 255) / 256, 256, 0, stream>>>(qkvb, cosb, sinb);

  // 4) V transpose
  vtrans_kernel<<<NB_B * NB_KV * (NB_S / 64), 256, 0, stream>>>(qkvb, vtb);

  // 5) flash attention
  attn_kernel<<<NB_B * NB_H * (NB_S / 64), 256, 0, stream>>>(qkvb, vtb, ob);

  // 6) output projection: [4096][2048] x [2048][2048]^T -> fp32 out
  gemm_bt<<<dim3(NB_D / 128, NB_M / 128), 256, 0, stream>>>(ob, wob, nullptr, out,
                                                            NB_M, NB_D, NB_D);
}

// Round 2
// 353.490 us; speedup vs baseline: 1.7037x; 1.7037x over previous
//
#include <hip/hip_runtime.h>
#include <hip/hip_bf16.h>
#include <stdint.h>

typedef __bf16 bf16x8 __attribute__((ext_vector_type(8)));
typedef float f32x4 __attribute__((ext_vector_type(4)));
typedef float f32x16 __attribute__((ext_vector_type(16)));

#define NB_H 16
#define NB_KV 4
#define NB_HD 128
#define NB_B 2
#define NB_S 2048
#define NB_D 2048
#define NB_M (NB_B*NB_S)   /* 4096 */
#define NB_NQKV 3072
#define CAPF 50.0f
#define SCALEF 0.08838834764831845f

__device__ __forceinline__ ushort f2bf(float x){
  uint32_t u = __float_as_uint(x);
  u += 0x7fffu + ((u >> 16) & 1u);
  return (ushort)(u >> 16);
}
__device__ __forceinline__ float bf2f(ushort u){
  return __uint_as_float(((uint32_t)u) << 16);
}
__device__ __forceinline__ uint pk2(float lo, float hi2){
  return ((uint)f2bf(hi2) << 16) | (uint)f2bf(lo);
}
__device__ __forceinline__ void gload_lds16(const void* g, void* l){
  __builtin_amdgcn_global_load_lds(
      (const __attribute__((address_space(1))) uint32_t*)g,
      (__attribute__((address_space(3))) uint32_t*)l, 16, 0, 0);
}

// ---------------- fp32 -> bf16 conversion ----------------
__global__ __launch_bounds__(256) void cvt_kernel(const float* __restrict__ in,
                                                  ushort* __restrict__ out, int n){
  int idx = blockIdx.x * blockDim.x + threadIdx.x;
  int i4 = idx * 4;
  if (i4 >= n) return;
  float4 v = *(const float4*)(in + i4);
  ushort4 o;
  o.x = f2bf(v.x); o.y = f2bf(v.y); o.z = f2bf(v.z); o.w = f2bf(v.w);
  *(ushort4*)(out + i4) = o;
}

// ---------------- bf16 GEMM: C[M][N] = A[M][K] * B[N][K]^T ----------------
__global__ __launch_bounds__(256) void gemm_bt(const ushort* __restrict__ A,
                                               const ushort* __restrict__ Bw,
                                               ushort* __restrict__ Cb,
                                               float* __restrict__ Cf,
                                               int M, int N, int K){
  __shared__ ushort As[128 * 32];
  __shared__ ushort Bs[128 * 32];
  int tid = threadIdx.x;
  int w = tid >> 6, l = tid & 63;
  int lr = l & 15, lk = l >> 4;
  int row0 = blockIdx.y * 128, col0 = blockIdx.x * 128;
  int wm = w >> 1, wn = w & 1;

  f32x4 acc[4][4];
#pragma unroll
  for (int mi = 0; mi < 4; ++mi)
#pragma unroll
    for (int nj = 0; nj < 4; ++nj)
      acc[mi][nj] = f32x4{0.f, 0.f, 0.f, 0.f};

  for (int k0 = 0; k0 < K; k0 += 32) {
#pragma unroll
    for (int c = 0; c < 2; ++c) {
      int off = w * 2048 + c * 1024 + l * 16;
      int r = off >> 6;
      int cb = off & 63;
      gload_lds16(A + (size_t)(row0 + r) * K + k0 + (cb >> 1), (char*)As + off);
      gload_lds16(Bw + (size_t)(col0 + r) * K + k0 + (cb >> 1), (char*)Bs + off);
    }
    __syncthreads();
    bf16x8 af[4], bfr[4];
#pragma unroll
    for (int mi = 0; mi < 4; ++mi)
      af[mi] = *(const bf16x8*)(As + (wm * 64 + mi * 16 + lr) * 32 + lk * 8);
#pragma unroll
    for (int nj = 0; nj < 4; ++nj)
      bfr[nj] = *(const bf16x8*)(Bs + (wn * 64 + nj * 16 + lr) * 32 + lk * 8);
#pragma unroll
    for (int mi = 0; mi < 4; ++mi)
#pragma unroll
      for (int nj = 0; nj < 4; ++nj)
        acc[mi][nj] = __builtin_amdgcn_mfma_f32_16x16x32_bf16(af[mi], bfr[nj], acc[mi][nj], 0, 0, 0);
    __syncthreads();
  }

#pragma unroll
  for (int mi = 0; mi < 4; ++mi)
#pragma unroll
    for (int nj = 0; nj < 4; ++nj)
#pragma unroll
      for (int i = 0; i < 4; ++i) {
        int r = row0 + wm * 64 + mi * 16 + lk * 4 + i;
        int c = col0 + wn * 64 + nj * 16 + lr;
        float v = acc[mi][nj][i];
        if (Cb) Cb[(size_t)r * N + c] = f2bf(v);
        else    Cf[(size_t)r * N + c] = v;
      }
}

// ---------------- RoPE in-place on Q (heads 0..15) and K (heads 16..19) ----------------
__global__ __launch_bounds__(256) void rope_kernel(ushort* __restrict__ qkv,
                                                   const float* __restrict__ cosb,
                                                   const float* __restrict__ sinb){
  int idx = blockIdx.x * blockDim.x + threadIdx.x;
  if (idx >= NB_M * 20 * 64) return;
  int row = idx / 1280;
  int rem = idx - row * 1280;
  int head = rem >> 6;
  int d = rem & 63;
  size_t base = (size_t)row * NB_NQKV + head * 128 + d;
  float a = bf2f(qkv[base]);
  float b = bf2f(qkv[base + 64]);
  float c = cosb[row * 128 + d];
  float s = sinb[row * 128 + d];
  qkv[base]      = f2bf(a * c - b * s);
  qkv[base + 64] = f2bf(b * c + a * s);
}

// ---------------- V transpose: vt[b][kv][d][s] ----------------
__global__ __launch_bounds__(256) void vtrans_kernel(const ushort* __restrict__ qkv,
                                                     ushort* __restrict__ vt){
  __shared__ ushort tile[64 * 136];
  int bid = blockIdx.x;
  int s0 = (bid & 31) * 64;
  int kvh = (bid >> 5) & 3;
  int b = bid >> 7;
  int tid = threadIdx.x;
#pragma unroll
  for (int i = 0; i < 4; ++i) {
    int g = tid + i * 256;
    int r = g >> 4, c = g & 15;
    *(uint4*)(tile + r * 136 + c * 8) =
        *(const uint4*)(qkv + (size_t)(b * NB_S + s0 + r) * NB_NQKV + 2560 + kvh * 128 + c * 8);
  }
  __syncthreads();
#pragma unroll
  for (int i = 0; i < 4; ++i) {
    int g = tid + i * 256;
    int dd = g >> 3, c = g & 7;
    union { ushort u[8]; uint4 v; } tmp;
#pragma unroll
    for (int j = 0; j < 8; ++j) tmp.u[j] = tile[(c * 8 + j) * 136 + dd];
    *(uint4*)(vt + ((size_t)(b * NB_KV + kvh) * NB_HD + dd) * NB_S + s0 + c * 8) = tmp.v;
  }
}

// ---------------- flash attention v2: 32x32 MFMA, swapped operands ----------------
// grid: 512 blocks; block = (bh, qt) with qt ordered [15..8, 0..7] for balance.
// 4 waves x 32 q-rows = 128 q/block; KVBLK=64; K/V double-buffered in swizzled LDS.
__global__ __launch_bounds__(256, 2) void attn_kernel(const ushort* __restrict__ qkv,
                                                      const ushort* __restrict__ vt,
                                                      ushort* __restrict__ obuf){
  __shared__ ushort lds[2][16384];   // per buf: K [64][128] (8192) | V^T [128][64] (8192)
  const int tid = threadIdx.x;
  const int w = tid >> 6, l = tid & 63;
  const int ql = l & 31, hi = l >> 5;
  const int blk = blockIdx.x;
  const int j = blk >> 5;
  const int qt = (j < 8) ? (15 - j) : (j - 8);
  const int bh = blk & 31;
  const int b = bh >> 4, h = bh & 15;
  const int kvh = h >> 2;
  const int qbase = qt * 128 + w * 32;
  const int q = qbase + ql;
  const int nkt = 2 * (qt + 1);

  // staging addresses (pre-swizzled global source -> linear global_load_lds dest)
  size_t kidx[4], vidx[4];
#pragma unroll
  for (int i = 0; i < 4; ++i) {
    int s = i * 256 + tid;
    int kr = s >> 4, kc = s & 15;
    int kg = (kc & 8) | ((kc ^ kr) & 7);
    kidx[i] = (size_t)(b * NB_S + kr) * NB_NQKV + 2048 + kvh * 128 + kg * 8;
    int vr = s >> 3, vc = s & 7;
    int vg = (vc ^ vr) & 7;
    vidx[i] = ((size_t)(b * NB_KV + kvh) * NB_HD + vr) * NB_S + vg * 8;
  }

  // Q fragments (B-operand: lane holds q-col = ql, d = 16*dc + 8*hi + j)
  bf16x8 qf[8];
  {
    const ushort* qrow = qkv + (size_t)(b * NB_S + q) * NB_NQKV + h * 128 + hi * 8;
#pragma unroll
    for (int dc = 0; dc < 8; ++dc)
      qf[dc] = *(const bf16x8*)(qrow + dc * 16);
  }

  f32x16 acc[4];   // O^T accumulator: acc[dt] = 32d x 32q tile, col q = ql
#pragma unroll
  for (int dt = 0; dt < 4; ++dt)
#pragma unroll
    for (int r = 0; r < 16; ++r) acc[dt][r] = 0.f;
  float m_run = -1e30f, l_run = 0.f;

  // prologue stage
#pragma unroll
  for (int i = 0; i < 4; ++i)
    gload_lds16(qkv + kidx[i], (char*)lds[0] + (i * 256 + tid) * 16);
#pragma unroll
  for (int i = 0; i < 4; ++i)
    gload_lds16(vt + vidx[i], (char*)lds[0] + 16384 + (i * 256 + tid) * 16);
  __syncthreads();

  int cur = 0;
  for (int kt = 0; kt < nkt; ++kt) {
    const int s0 = kt * 64;
    if (kt + 1 < nkt) {   // prefetch next tile into other buffer
      const size_t ks = (size_t)(kt + 1) * 64 * NB_NQKV;
      const int vs = (kt + 1) * 64;
#pragma unroll
      for (int i = 0; i < 4; ++i)
        gload_lds16(qkv + kidx[i] + ks, (char*)lds[cur ^ 1] + (i * 256 + tid) * 16);
#pragma unroll
      for (int i = 0; i < 4; ++i)
        gload_lds16(vt + vidx[i] + vs, (char*)lds[cur ^ 1] + 16384 + (i * 256 + tid) * 16);
    }
    const ushort* Kb = lds[cur];
    const ushort* Vb = lds[cur] + 8192;
    if (s0 <= qbase + 31) {   // wave-uniform skip of fully-masked tiles
      // S^T = mfma(K, Q): lane holds q = ql, k5 = (r&3)+8*(r>>2)+4*hi per tile
      f32x16 st[2];
#pragma unroll
      for (int t = 0; t < 2; ++t) {
#pragma unroll
        for (int r = 0; r < 16; ++r) st[t][r] = 0.f;
        const int krow = t * 32 + ql;
#pragma unroll
        for (int dc = 0; dc < 8; ++dc) {
          const int gd = dc * 2 + hi;
          const int g2 = (gd & 8) | ((gd ^ krow) & 7);
          bf16x8 kf = *(const bf16x8*)(Kb + krow * 128 + g2 * 8);
          st[t] = __builtin_amdgcn_mfma_f32_32x32x16_bf16(kf, qf[dc], st[t], 0, 0, 0);
        }
      }
      // tanh soft-cap + causal mask
      float p[2][16];
#pragma unroll
      for (int t = 0; t < 2; ++t)
#pragma unroll
        for (int r = 0; r < 16; ++r) {
          float x = st[t][r] * (2.0f * SCALEF / CAPF);
          x = fminf(fmaxf(x, -16.f), 16.f);
          float e = __expf(x);
          float capped = CAPF - (2.0f * CAPF) * __builtin_amdgcn_rcpf(e + 1.0f);
          int kg = s0 + t * 32 + (r & 3) + 8 * (r >> 2) + 4 * hi;
          p[t][r] = (kg <= q) ? capped : -1e30f;
        }
      // online softmax: per-lane stats (q is lane-local), one cross-half shfl
      float mt = -1e30f;
#pragma unroll
      for (int t = 0; t < 2; ++t)
#pragma unroll
        for (int r = 0; r < 16; ++r) mt = fmaxf(mt, p[t][r]);
      mt = fmaxf(mt, __shfl_xor(mt, 32));
      const float mn = fmaxf(m_run, mt);
      const float fac = __expf(m_run - mn);
      m_run = mn;
      float rs = 0.f;
#pragma unroll
      for (int t = 0; t < 2; ++t)
#pragma unroll
        for (int r = 0; r < 16; ++r) {
          float pe = __expf(p[t][r] - mn);
          p[t][r] = pe;
          rs += pe;
        }
      rs += __shfl_xor(rs, 32);
      l_run = l_run * fac + rs;
#pragma unroll
      for (int dt = 0; dt < 4; ++dt)
#pragma unroll
        for (int r = 0; r < 16; ++r) acc[dt][r] *= fac;
      // pack P to bf16 pairs and exchange halves for the P^T B-fragment
      uint ua[2][4], ub[2][4], pa[2][4], pb[2][4];
#pragma unroll
      for (int t = 0; t < 2; ++t)
#pragma unroll
        for (int g = 0; g < 4; ++g) {
          ua[t][g] = pk2(p[t][4 * g], p[t][4 * g + 1]);
          ub[t][g] = pk2(p[t][4 * g + 2], p[t][4 * g + 3]);
        }
#pragma unroll
      for (int t = 0; t < 2; ++t)
#pragma unroll
        for (int g = 0; g < 4; ++g) {
          pa[t][g] = __shfl_xor(ua[t][g], 32);
          pb[t][g] = __shfl_xor(ub[t][g], 32);
        }
      // O^T += mfma(V^T, P^T)
#pragma unroll
      for (int c = 0; c < 4; ++c) {
        const int t = c >> 1, hh = c & 1;
        union { uint u[4]; bf16x8 v; } pf;
        pf.u[0] = hi ? pa[t][2 * hh + 1] : ua[t][2 * hh];
        pf.u[1] = hi ? pb[t][2 * hh + 1] : ub[t][2 * hh];
        pf.u[2] = hi ? ua[t][2 * hh + 1] : pa[t][2 * hh];
        pf.u[3] = hi ? ub[t][2 * hh + 1] : pb[t][2 * hh];
#pragma unroll
        for (int dt = 0; dt < 4; ++dt) {
          const int vrow = dt * 32 + ql;
          const int gk = c * 2 + hi;
          const int g2 = (gk ^ vrow) & 7;
          bf16x8 vf = *(const bf16x8*)(Vb + vrow * 64 + g2 * 8);
          acc[dt] = __builtin_amdgcn_mfma_f32_32x32x16_bf16(vf, pf.v, acc[dt], 0, 0, 0);
        }
      }
    }
    __syncthreads();
    cur ^= 1;
  }

  // epilogue: O^T -> LDS transpose (per-wave region) -> coalesced global store
  const float inv = __builtin_amdgcn_rcpf(l_run);
  ushort* reg = (ushort*)lds + (size_t)w * 4352;   // 32 rows x 136
#pragma unroll
  for (int dt = 0; dt < 4; ++dt)
#pragma unroll
    for (int g = 0; g < 4; ++g) {
      ushort4 o;
      o.x = f2bf(acc[dt][4 * g + 0] * inv);
      o.y = f2bf(acc[dt][4 * g + 1] * inv);
      o.z = f2bf(acc[dt][4 * g + 2] * inv);
      o.w = f2bf(acc[dt][4 * g + 3] * inv);
      const int d0 = dt * 32 + g * 8 + hi * 4;
      *(ushort4*)(reg + ql * 136 + d0) = o;
    }
  __syncthreads();
#pragma unroll
  for (int i = 0; i < 8; ++i) {
    const int qr = i * 4 + (l >> 4);
    const int c = l & 15;
    uint4 v = *(const uint4*)(reg + qr * 136 + c * 8);
    *(uint4*)(obuf + (size_t)(b * NB_S + qbase + qr) * NB_D + h * 128 + c * 8) = v;
  }
}

// ---------------- host launch ----------------
extern "C" void kernel_launch(void* const* d_in, const int* in_sizes, int n_in,
                              void* d_out, int out_size, void* d_ws, size_t ws_size,
                              hipStream_t stream) {
  const float* hs   = (const float*)d_in[0];
  const float* cosb = (const float*)d_in[1];
  const float* sinb = (const float*)d_in[2];
  const float* Wq   = (const float*)d_in[3];
  const float* Wk   = (const float*)d_in[4];
  const float* Wv   = (const float*)d_in[5];
  const float* Wo   = (const float*)d_in[6];
  float* out = (float*)d_out;
  char* ws = (char*)d_ws;

  ushort* hsb  = (ushort*)(ws + 0);
  ushort* wqkv = (ushort*)(ws + 16777216);
  ushort* wob  = (ushort*)(ws + 29360128);
  ushort* qkvb = (ushort*)(ws + 37748736);
  ushort* vtb  = (ushort*)(ws + 62914560);
  ushort* ob   = (ushort*)(ws + 67108864);

  cvt_kernel<<<(NB_M * NB_D / 4 + 255) / 256, 256, 0, stream>>>(hs, hsb, NB_M * NB_D);
  cvt_kernel<<<(NB_H * NB_HD * NB_D / 4 + 255) / 256, 256, 0, stream>>>(Wq, wqkv, NB_H * NB_HD * NB_D);
  cvt_kernel<<<(NB_KV * NB_HD * NB_D / 4 + 255) / 256, 256, 0, stream>>>(Wk, wqkv + 2048 * 2048, NB_KV * NB_HD * NB_D);
  cvt_kernel<<<(NB_KV * NB_HD * NB_D / 4 + 255) / 256, 256, 0, stream>>>(Wv, wqkv + 2560 * 2048, NB_KV * NB_HD * NB_D);
  cvt_kernel<<<(NB_D * NB_D / 4 + 255) / 256, 256, 0, stream>>>(Wo, wob, NB_D * NB_D);

  gemm_bt<<<dim3(NB_NQKV / 128, NB_M / 128), 256, 0, stream>>>(hsb, wqkv, qkvb, nullptr,
                                                               NB_M, NB_NQKV, NB_D);
  rope_kernel<<<(NB_M * 20 * 64 + 255) / 256, 256, 0, stream>>>(qkvb, cosb, sinb);
  vtrans_kernel<<<NB_B * NB_KV * (NB_S / 64), 256, 0, stream>>>(qkvb, vtb);

  attn_kernel<<<512, 256, 0, stream>>>(qkvb, vtb, ob);

  gemm_bt<<<dim3(NB_D / 128, NB_M / 128), 256, 0, stream>>>(ob, wob, nullptr, out,
                                                            NB_M, NB_D, NB_D);
}